// Round 9
// baseline (1092.421 us; speedup 1.0000x reference)
//
#include <hip/hip_runtime.h>

typedef __attribute__((ext_vector_type(8))) short bf16x8;
typedef __attribute__((ext_vector_type(4))) short bf16x4;
typedef __attribute__((ext_vector_type(16))) float f32x16;

#define TFULL 8192
#define RC 128
#define NB 40
#define BATCH 4
#define SKIP_SZ 4096

// LDS: 2 planes of [64 col][256 B], chunk-XOR-swizzled (16B-chunk ^= col&15).
// Planes hold: current tap X hi/lo during dilated; then gated hi/lo.
// Epilogue residual re-reads X from global (L2-hot).
#define XPLANE 16384
#define LDS_BYTES (2 * XPLANE)   // 32768 B

#define LDS3(p) ((__attribute__((address_space(3))) void*)(p))
#define GLB1(p) ((const __attribute__((address_space(1))) void*)(p))

__device__ __forceinline__ unsigned short f2bf(float f) {
    unsigned u = __builtin_bit_cast(unsigned, f);
    u += 0x7FFFu + ((u >> 16) & 1u);          // round-to-nearest-even
    return (unsigned short)(u >> 16);
}
__device__ __forceinline__ float bf2f(unsigned short h) {
    unsigned u = ((unsigned)h) << 16;
    return __builtin_bit_cast(float, u);
}
// tanh(y)*sigmoid(y) via one fast exp (clamped; saturation exact).
__device__ __forceinline__ float gatef(float y) {
    float yc = fminf(fmaxf(y, -30.f), 30.f);
    float e  = __expf(-yc);
    float e2 = e * e;
    return (1.f - e2) * __builtin_amdgcn_rcpf(1.f + e2)
                      * __builtin_amdgcn_rcpf(1.f + e);
}

// ---------------------------------------------------------------------------
// Pre-pass 1: transpose x [B][128ch][8192col] fp32 -> hi/lo bf16 [B][col][ch]
// ---------------------------------------------------------------------------
__global__ __launch_bounds__(256) void xpose_split(
    const float* __restrict__ x,
    unsigned short* __restrict__ Xh, unsigned short* __restrict__ Xl)
{
    __shared__ float t[32][65];
    const int col0 = blockIdx.x * 64;
    const int ch0  = blockIdx.y * 32;
    const int b    = blockIdx.z;
    const int tid  = threadIdx.x;
    const int tx = tid & 63, ty = tid >> 6;
#pragma unroll
    for (int i = 0; i < 8; ++i) {
        int ch = ty + i * 4;
        t[ch][tx] = x[((size_t)(b * RC + ch0 + ch)) * TFULL + col0 + tx];
    }
    __syncthreads();
    for (int idx = tid; idx < 64 * 32; idx += 256) {
        int col = idx >> 5, ch = idx & 31;
        float v = t[ch][col];
        unsigned short h = f2bf(v);
        unsigned short l = f2bf(v - bf2f(h));
        size_t off = ((size_t)(b * TFULL + col0 + col)) * RC + ch0 + ch;
        Xh[off] = h;
        Xl[off] = l;
    }
}

// ---------------------------------------------------------------------------
// Pre-pass 2: pack weights into 32x32x16 A-fragment layout, hi/lo bf16.
// A[m][k]: lane holds m = mt*32 + (lane&31), k = (lane>>5)*8 + j within a
// K=16 slice. Dilated K=256 tap-major: ks 0..15, tap = ks>>3,
// ch = (ks&7)*16 + (lane>>5)*8 + j. Res/skip: ks 0..7, k = ks*16 + ...
// Dst flat: ((blk*KS + ks)*4 + mt)*512 + lane*8 + j.
// ---------------------------------------------------------------------------
__global__ __launch_bounds__(256) void wpack(
    const float* __restrict__ Wd, const float* __restrict__ Wr, const float* __restrict__ Ws,
    unsigned short* __restrict__ Wdh, unsigned short* __restrict__ Wdl,
    unsigned short* __restrict__ Wrh, unsigned short* __restrict__ Wrl,
    unsigned short* __restrict__ Wsh, unsigned short* __restrict__ Wsl)
{
    const int Nd = NB * 4096;   // 16ks * 4mt * 64lane
    const int Nr = NB * 2048;   // 8ks  * 4mt * 64lane
    int id = blockIdx.x * 256 + threadIdx.x;
    const float* src;
    unsigned short *dh, *dl;
    int blk, rloc;
    bool dil = false;
    size_t dbase;
    if (id < Nd)               { dil = true; blk = id >> 12; rloc = id & 4095; dh = Wdh; dl = Wdl; src = Wd; dbase = (size_t)id * 8; }
    else if (id < Nd + Nr)     { int t = id - Nd;      blk = t >> 11; rloc = t & 2047; dh = Wrh; dl = Wrl; src = Wr; dbase = (size_t)t * 8; }
    else if (id < Nd + 2 * Nr) { int t = id - Nd - Nr; blk = t >> 11; rloc = t & 2047; dh = Wsh; dl = Wsl; src = Ws; dbase = (size_t)t * 8; }
    else return;
    const int ks   = rloc >> 8;            // 0..15 dil, 0..7 res/skip
    const int mt   = (rloc >> 6) & 3;
    const int lane = rloc & 63;
    const int m    = mt * 32 + (lane & 31);
    const int kj   = ((lane >> 5) << 3);
    bf16x8 hv, lv;
#pragma unroll
    for (int j = 0; j < 8; ++j) {
        float w;
        if (dil) {
            const int tap = ks >> 3;
            const int ch  = (ks & 7) * 16 + kj + j;
            w = src[((((size_t)blk * 128 + m) * 128) + ch) * 2 + tap];
        } else {
            const int k = ks * 16 + kj + j;
            w = src[(((size_t)blk * 128 + m) * 128) + k];
        }
        unsigned short h = f2bf(w);
        hv[j] = (short)h;
        lv[j] = (short)f2bf(w - bf2f(h));
    }
    *(bf16x8*)(dh + dbase) = hv;
    *(bf16x8*)(dl + dbase) = lv;
}

// ---------------------------------------------------------------------------
// One WaveNet block step. 256 thr = 4 waves; WG tile = 128 out-ch x 64 col.
// Wave = one 32-ch m-tile (mt = wave) x 64 cols (2 n-tiles of 32), via
// mfma_f32_32x32x16_bf16 -> zero intra-WG weight duplication, half the
// LDS B-reads per FLOP of the 16x16 version. Taps staged sequentially into
// one hi/lo plane pair; gated overwrites it; epilogue re-reads X from L2.
// 3-product hi/lo bf16 splitting (AhBh + AhBl + AlBh).
// ---------------------------------------------------------------------------
__global__ __launch_bounds__(256, 2) void wn_step(
    const unsigned short* __restrict__ curh, const unsigned short* __restrict__ curl,
    unsigned short* __restrict__ nxth, unsigned short* __restrict__ nxtl,
    const unsigned short* __restrict__ Wdh_i, const unsigned short* __restrict__ Wdl_i,
    const unsigned short* __restrict__ Wrh_i, const unsigned short* __restrict__ Wrl_i,
    const unsigned short* __restrict__ Wsh_i, const unsigned short* __restrict__ Wsl_i,
    const float* __restrict__ br, const float* __restrict__ bs,
    float* __restrict__ skip, int d, int col0)
{
    __shared__ char lds[LDS_BYTES];

    const int tid  = threadIdx.x;
    const int lane = tid & 63;
    const int wave = tid >> 6;            // 0..3 = mt
    const int l31  = lane & 31;
    const int l5   = lane >> 5;           // 0/1
    const int lq   = (lane >> 4) & 3;
    const int l15  = lane & 15;
    const int u    = blockIdx.x;
    const int b    = u & 3;
    const int tile0 = col0 + (u >> 2) * 64;
    const size_t xbase = (size_t)b * TFULL * RC;

    f32x16 accd[2];
#pragma unroll
    for (int nt = 0; nt < 2; ++nt)
#pragma unroll
        for (int r = 0; r < 16; ++r) accd[nt][r] = 0.f;

    // ---- dilated conv: per tap, stage X hi/lo then 8 K=16 steps
#pragma unroll
    for (int tap = 0; tap < 2; ++tap) {
        if (tap) __syncthreads();   // WAR: all waves done reading prev tap
        {   // stage: 32 x (64-lane x 16B) global_load_lds, linear LDS dest,
            // pre-swizzled global source chunk (chunk ^ (col&15)).
            const int cshift = tap ? 0 : d;
#pragma unroll
            for (int r = 0; r < 8; ++r) {
                const int j   = wave * 8 + r;      // 0..31
                const int hl  = j >> 4;
                const int c4  = (j & 15) * 4;
                const int col = c4 + lq;
                const int chs = l15 ^ (col & 15);
                int cg_ = tile0 + col;
                cg_ = cg_ > TFULL - 1 ? TFULL - 1 : cg_;   // tail clamp
                cg_ -= cshift;
                const unsigned short* gsrc =
                    (hl ? curl : curh) + xbase + (size_t)cg_ * RC + chs * 8;
                char* ldst = lds + hl * XPLANE + c4 * 256;  // wave-uniform
                __builtin_amdgcn_global_load_lds(GLB1(gsrc), LDS3(ldst), 16, 0, 0);
            }
        }
        __syncthreads();

#pragma unroll
        for (int kk = 0; kk < 8; ++kk) {
            const int ks = tap * 8 + kk;
            const size_t wi = ((size_t)(ks * 4 + wave) * 64 + lane) * 8;
            bf16x8 ah = *(const bf16x8*)(Wdh_i + wi);
            bf16x8 al = *(const bf16x8*)(Wdl_i + wi);
#pragma unroll
            for (int nt = 0; nt < 2; ++nt) {
                const int col = nt * 32 + l31;
                const int byo = (kk * 32 + l5 * 16) ^ ((col & 15) << 4);
                const char* pb = lds + col * 256 + byo;
                bf16x8 bh = *(const bf16x8*)pb;
                bf16x8 bl = *(const bf16x8*)(pb + XPLANE);
                accd[nt] = __builtin_amdgcn_mfma_f32_32x32x16_bf16(ah, bh, accd[nt], 0, 0, 0);
                accd[nt] = __builtin_amdgcn_mfma_f32_32x32x16_bf16(ah, bl, accd[nt], 0, 0, 0);
                accd[nt] = __builtin_amdgcn_mfma_f32_32x32x16_bf16(al, bh, accd[nt], 0, 0, 0);
            }
        }
    }
    __syncthreads();   // WAR: all waves done reading tap1 planes

    // ---- gate + write gated hi/lo into the (now dead) X planes.
    // C/D: col = l31 (+nt*32), row = (reg&3) + 8*(reg>>2) + 4*l5.
#pragma unroll
    for (int nt = 0; nt < 2; ++nt) {
        const int n = nt * 32 + l31;
#pragma unroll
        for (int q = 0; q < 4; ++q) {
            const int chb = wave * 32 + q * 8 + l5 * 4;   // 4 consecutive ch
            const int byo = (chb * 2) ^ ((n & 15) << 4);
            bf16x4 hv, lv;
#pragma unroll
            for (int rr = 0; rr < 4; ++rr) {
                float g = gatef(accd[nt][q * 4 + rr]);
                unsigned short h = f2bf(g);
                hv[rr] = (short)h;
                lv[rr] = (short)f2bf(g - bf2f(h));
            }
            char* pg = lds + n * 256 + byo;
            *(bf16x4*)pg = hv;
            *(bf16x4*)(pg + XPLANE) = lv;
        }
    }
    __syncthreads();

    // ---- res & skip GEMMs: K = 128 over gated, 8 K=16 steps
    f32x16 accr[2], accs[2];
#pragma unroll
    for (int nt = 0; nt < 2; ++nt)
#pragma unroll
        for (int r = 0; r < 16; ++r) { accr[nt][r] = 0.f; accs[nt][r] = 0.f; }

#pragma unroll
    for (int ks = 0; ks < 8; ++ks) {
        const size_t wi = ((size_t)(ks * 4 + wave) * 64 + lane) * 8;
        bf16x8 rh = *(const bf16x8*)(Wrh_i + wi);
        bf16x8 rl = *(const bf16x8*)(Wrl_i + wi);
        bf16x8 sh = *(const bf16x8*)(Wsh_i + wi);
        bf16x8 sl = *(const bf16x8*)(Wsl_i + wi);
#pragma unroll
        for (int nt = 0; nt < 2; ++nt) {
            const int col = nt * 32 + l31;
            const int byo = (ks * 32 + l5 * 16) ^ ((col & 15) << 4);
            const char* pg = lds + col * 256 + byo;
            bf16x8 gh = *(const bf16x8*)pg;
            bf16x8 gl = *(const bf16x8*)(pg + XPLANE);
            accr[nt] = __builtin_amdgcn_mfma_f32_32x32x16_bf16(rh, gh, accr[nt], 0, 0, 0);
            accr[nt] = __builtin_amdgcn_mfma_f32_32x32x16_bf16(rh, gl, accr[nt], 0, 0, 0);
            accr[nt] = __builtin_amdgcn_mfma_f32_32x32x16_bf16(rl, gh, accr[nt], 0, 0, 0);
            accs[nt] = __builtin_amdgcn_mfma_f32_32x32x16_bf16(sh, gh, accs[nt], 0, 0, 0);
            accs[nt] = __builtin_amdgcn_mfma_f32_32x32x16_bf16(sh, gl, accs[nt], 0, 0, 0);
            accs[nt] = __builtin_amdgcn_mfma_f32_32x32x16_bf16(sl, gh, accs[nt], 0, 0, 0);
        }
    }

    // ---- epilogue: residual add (X hi/lo re-read from global, L2-hot),
    // re-split stream, store Y hi/lo + skip fp32.
    const int ntv = TFULL - tile0 < 64 ? TFULL - tile0 : 64;
#pragma unroll
    for (int nt = 0; nt < 2; ++nt) {
        const int n = nt * 32 + l31;
        const int c = tile0 + n;
        if (n < ntv) {
#pragma unroll
            for (int q = 0; q < 4; ++q) {
                const int chb = wave * 32 + q * 8 + l5 * 4;
                const size_t off = xbase + (size_t)c * RC + chb;
                bf16x4 ih = *(const bf16x4*)(curh + off);
                bf16x4 il = *(const bf16x4*)(curl + off);
                const float4 brv = *(const float4*)(br + chb);
                const float4 bsv = *(const float4*)(bs + chb);
                bf16x4 oh, ol;
                float sk[4];
#pragma unroll
                for (int rr = 0; rr < 4; ++rr) {
                    float inv = bf2f((unsigned short)ih[rr]) + bf2f((unsigned short)il[rr]);
                    float rv = accr[nt][q * 4 + rr] + ((const float*)&brv)[rr] + inv;
                    unsigned short h = f2bf(rv);
                    oh[rr] = (short)h;
                    ol[rr] = (short)f2bf(rv - bf2f(h));
                    sk[rr] = accs[nt][q * 4 + rr] + ((const float*)&bsv)[rr];
                }
                *(bf16x4*)(nxth + off) = oh;
                *(bf16x4*)(nxtl + off) = ol;
                if (c >= TFULL - SKIP_SZ) {
                    float* sp = skip + ((size_t)b * RC + chb) * SKIP_SZ + (c - (TFULL - SKIP_SZ));
#pragma unroll
                    for (int rr = 0; rr < 4; ++rr) sp[(size_t)rr * SKIP_SZ] = sk[rr];
                }
            }
        }
    }
}

extern "C" void kernel_launch(void* const* d_in, const int* in_sizes, int n_in,
                              void* d_out, int out_size, void* d_ws, size_t ws_size,
                              hipStream_t stream) {
    const float* x  = (const float*)d_in[0];
    const float* Wd = (const float*)d_in[1];
    const float* Wr = (const float*)d_in[2];
    const float* br = (const float*)d_in[3];
    const float* Ws = (const float*)d_in[4];
    const float* bs = (const float*)d_in[5];
    float* out = (float*)d_out;

    const size_t SLOT = (size_t)BATCH * TFULL * RC;
    unsigned short* Xs0h = (unsigned short*)d_ws;
    unsigned short* Xs0l = Xs0h + SLOT;
    unsigned short* Xs1h = Xs0l + SLOT;
    unsigned short* Xs1l = Xs1h + SLOT;
    unsigned short* Wdh = Xs1l + SLOT;
    unsigned short* Wdl = Wdh + (size_t)NB * 32768;
    unsigned short* Wrh = Wdl + (size_t)NB * 32768;
    unsigned short* Wrl = Wrh + (size_t)NB * 16384;
    unsigned short* Wsh = Wrl + (size_t)NB * 16384;
    unsigned short* Wsl = Wsh + (size_t)NB * 16384;

    xpose_split<<<dim3(TFULL / 64, RC / 32, BATCH), 256, 0, stream>>>(x, Xs0h, Xs0l);
    {
        int total = NB * 4096 + 2 * NB * 2048;
        wpack<<<dim3((total + 255) / 256), 256, 0, stream>>>(Wd, Wr, Ws, Wdh, Wdl, Wrh, Wrl, Wsh, Wsl);
    }

    int L = TFULL;
    int pp = 0;
    for (int i = 0; i < NB; ++i) {
        const int d = 1 << (i % 10);
        const int Lout = L - d;
        const int col0 = TFULL - Lout;
        const int units = ((Lout + 63) >> 6) * BATCH;
        unsigned short* curh = pp ? Xs1h : Xs0h;
        unsigned short* curl = pp ? Xs1l : Xs0l;
        unsigned short* nxth = pp ? Xs0h : Xs1h;
        unsigned short* nxtl = pp ? Xs0l : Xs1l;
        wn_step<<<dim3(units), dim3(256), 0, stream>>>(
            curh, curl, nxth, nxtl,
            Wdh + (size_t)i * 32768, Wdl + (size_t)i * 32768,
            Wrh + (size_t)i * 16384, Wrl + (size_t)i * 16384,
            Wsh + (size_t)i * 16384, Wsl + (size_t)i * 16384,
            br + (size_t)i * RC, bs + (size_t)i * RC,
            out + (size_t)i * BATCH * RC * SKIP_SZ, d, col0);
        pp ^= 1;
        L = Lout;
    }
}

// Round 10
// 745.621 us; speedup vs baseline: 1.4651x; 1.4651x over previous
//
#include <hip/hip_runtime.h>

typedef __attribute__((ext_vector_type(8))) short bf16x8;
typedef __attribute__((ext_vector_type(4))) short bf16x4;
typedef __attribute__((ext_vector_type(4))) float f32x4;

#define TFULL 8192
#define RC 128
#define NB 40
#define BATCH 4
#define SKIP_SZ 4096

// LDS: 3 planes of [64 col][256 B], chunk-XOR swizzle (16B-chunk ^= col&7).
//   plane 0: X tap0 (bf16 hi only)   plane 1: X tap1 (hi; epilogue re-reads)
//   plane 2: gated (plain bf16)
#define XPLANE 16384
#define LDS_BYTES (3 * XPLANE)   // 49152 B -> 2 WG/CU (VGPR caps at 16 waves/CU anyway)

#define LDS3(p) ((__attribute__((address_space(3))) void*)(p))
#define GLB1(p) ((const __attribute__((address_space(1))) void*)(p))

__device__ __forceinline__ unsigned short f2bf(float f) {
    unsigned u = __builtin_bit_cast(unsigned, f);
    u += 0x7FFFu + ((u >> 16) & 1u);          // round-to-nearest-even
    return (unsigned short)(u >> 16);
}
__device__ __forceinline__ float bf2f(unsigned short h) {
    unsigned u = ((unsigned)h) << 16;
    return __builtin_bit_cast(float, u);
}
// tanh(y)*sigmoid(y) via one fast exp (clamped; saturation exact).
__device__ __forceinline__ float gatef(float y) {
    float yc = fminf(fmaxf(y, -30.f), 30.f);
    float e  = __expf(-yc);
    float e2 = e * e;
    return (1.f - e2) * __builtin_amdgcn_rcpf(1.f + e2)
                      * __builtin_amdgcn_rcpf(1.f + e);
}

// ---------------------------------------------------------------------------
// Pre-pass 1: transpose x [B][128ch][8192col] fp32 -> hi/lo bf16 [B][col][ch]
// ---------------------------------------------------------------------------
__global__ __launch_bounds__(256) void xpose_split(
    const float* __restrict__ x,
    unsigned short* __restrict__ Xh, unsigned short* __restrict__ Xl)
{
    __shared__ float t[32][65];
    const int col0 = blockIdx.x * 64;
    const int ch0  = blockIdx.y * 32;
    const int b    = blockIdx.z;
    const int tid  = threadIdx.x;
    const int tx = tid & 63, ty = tid >> 6;
#pragma unroll
    for (int i = 0; i < 8; ++i) {
        int ch = ty + i * 4;
        t[ch][tx] = x[((size_t)(b * RC + ch0 + ch)) * TFULL + col0 + tx];
    }
    __syncthreads();
    for (int idx = tid; idx < 64 * 32; idx += 256) {
        int col = idx >> 5, ch = idx & 31;
        float v = t[ch][col];
        unsigned short h = f2bf(v);
        unsigned short l = f2bf(v - bf2f(h));
        size_t off = ((size_t)(b * TFULL + col0 + col)) * RC + ch0 + ch;
        Xh[off] = h;
        Xl[off] = l;
    }
}

// ---------------------------------------------------------------------------
// Pre-pass 2: pack weights into per-MFMA-A-fragment layout, hi/lo bf16.
// A[m][k]: lane l holds rows m=16*mf+(l&15), k = 32*ks + (l>>4)*8 + j.
// Dilated k = tap*128 + i. Dst flat: ((blk*KS*8 + ks*8 + mf)*64 + lane)*8 + j.
// ---------------------------------------------------------------------------
__global__ __launch_bounds__(256) void wpack(
    const float* __restrict__ Wd, const float* __restrict__ Wr, const float* __restrict__ Ws,
    unsigned short* __restrict__ Wdh, unsigned short* __restrict__ Wdl,
    unsigned short* __restrict__ Wrh, unsigned short* __restrict__ Wrl,
    unsigned short* __restrict__ Wsh, unsigned short* __restrict__ Wsl)
{
    const int Nd = NB * 4096;
    const int Nr = NB * 2048;
    int id = blockIdx.x * 256 + threadIdx.x;
    const float* src;
    unsigned short *dh, *dl;
    int blk, rloc;
    bool dil = false;
    size_t dbase;
    if (id < Nd)               { dil = true; blk = id >> 12; rloc = id & 4095; dh = Wdh; dl = Wdl; src = Wd; dbase = (size_t)id * 8; }
    else if (id < Nd + Nr)     { int t = id - Nd;      blk = t >> 11; rloc = t & 2047; dh = Wrh; dl = Wrl; src = Wr; dbase = (size_t)t * 8; }
    else if (id < Nd + 2 * Nr) { int t = id - Nd - Nr; blk = t >> 11; rloc = t & 2047; dh = Wsh; dl = Wsl; src = Ws; dbase = (size_t)t * 8; }
    else return;
    const int ks = rloc >> 9, mf = (rloc >> 6) & 7, lane = rloc & 63;
    const int m = mf * 16 + (lane & 15);
    const int kb = ks * 32 + ((lane >> 4) << 3);
    bf16x8 hv, lv;
#pragma unroll
    for (int j = 0; j < 8; ++j) {
        int k = kb + j;
        float w;
        if (dil) {
            int tap = k >> 7, i = k & 127;
            w = src[((((size_t)blk * 128 + m) * 128) + i) * 2 + tap];
        } else {
            w = src[(((size_t)blk * 128 + m) * 128) + k];
        }
        unsigned short h = f2bf(w);
        hv[j] = (short)h;
        lv[j] = (short)f2bf(w - bf2f(h));
    }
    *(bf16x8*)(dh + dbase) = hv;
    *(bf16x8*)(dl + dbase) = lv;
}

// ---------------------------------------------------------------------------
// One WaveNet block step. 512 thr = 8 waves (R6 shape: wave = mf slot of
// 16 out-ch x 64 cols). Precision plan: weights hi/lo (2-product), X enters
// conv as plain bf16 (=Xh), gated plain bf16; residual stream kept exact
// hi/lo via epilogue (Xh from LDS, Xl from global). 2 barriers total.
// ---------------------------------------------------------------------------
__global__ __launch_bounds__(512, 4) void wn_step(
    const unsigned short* __restrict__ curh, const unsigned short* __restrict__ curl,
    unsigned short* __restrict__ nxth, unsigned short* __restrict__ nxtl,
    const unsigned short* __restrict__ Wdh_i, const unsigned short* __restrict__ Wdl_i,
    const unsigned short* __restrict__ Wrh_i, const unsigned short* __restrict__ Wrl_i,
    const unsigned short* __restrict__ Wsh_i, const unsigned short* __restrict__ Wsl_i,
    const float* __restrict__ br, const float* __restrict__ bs,
    float* __restrict__ skip, int d, int col0)
{
    __shared__ char lds[LDS_BYTES];

    const int tid  = threadIdx.x;
    const int lane = tid & 63;
    const int wave = tid >> 6;            // 0..7 = mf slot
    const int l15  = lane & 15, lq = lane >> 4;
    const int u    = blockIdx.x;
    const int b    = u & 3;
    const int tile0 = col0 + (u >> 2) * 64;
    const size_t xbase = (size_t)b * TFULL * RC;

    // ---- stage BOTH taps (Xh only): 32 x (64-lane x 16B) global_load_lds.
    // LDS linear (col, chunk); global source chunk pre-swizzled (^ col&7).
#pragma unroll
    for (int r = 0; r < 4; ++r) {
        const int j   = wave * 4 + r;      // 0..31
        const int tap = j >> 4;
        const int c4  = (j & 15) * 4;
        const int col = c4 + lq;
        const int chs = l15 ^ (col & 7);
        int cg_ = tile0 + col;
        cg_ = cg_ > TFULL - 1 ? TFULL - 1 : cg_;   // tail clamp
        if (!tap) cg_ -= d;
        const unsigned short* gsrc = curh + xbase + (size_t)cg_ * RC + chs * 8;
        char* ldst = lds + tap * XPLANE + c4 * 256;  // wave-uniform
        __builtin_amdgcn_global_load_lds(GLB1(gsrc), LDS3(ldst), 16, 0, 0);
    }
    __syncthreads();

    // ---- dilated conv GEMM: 8 unbroken ks steps, 2-product (Wh,Wl x Xh)
    f32x4 acc[4];
#pragma unroll
    for (int nf = 0; nf < 4; ++nf) acc[nf] = (f32x4){0.f, 0.f, 0.f, 0.f};

#pragma unroll
    for (int ks = 0; ks < 8; ++ks) {
        const int tap = ks >> 2;
        const int kk  = ks & 3;
        const size_t wi = ((size_t)(ks * 8 + wave) * 64 + lane) * 8;
        bf16x8 ah = *(const bf16x8*)(Wdh_i + wi);
        bf16x8 al = *(const bf16x8*)(Wdl_i + wi);
#pragma unroll
        for (int nf = 0; nf < 4; ++nf) {
            const int col = nf * 16 + l15;
            const int byo = (kk * 64 + lq * 16) ^ ((col & 7) << 4);
            bf16x8 bh = *(const bf16x8*)(lds + tap * XPLANE + col * 256 + byo);
            acc[nf] = __builtin_amdgcn_mfma_f32_16x16x32_bf16(ah, bh, acc[nf], 0, 0, 0);
            acc[nf] = __builtin_amdgcn_mfma_f32_16x16x32_bf16(al, bh, acc[nf], 0, 0, 0);
        }
    }

    // ---- gate + write gated (plain bf16) to plane 2
    const int ch0 = wave * 16 + lq * 4;
#pragma unroll
    for (int nf = 0; nf < 4; ++nf) {
        const int n   = nf * 16 + l15;
        const int byo = (ch0 * 2) ^ ((n & 7) << 4);
        bf16x4 hv;
#pragma unroll
        for (int r = 0; r < 4; ++r)
            hv[r] = (short)f2bf(gatef(acc[nf][r]));
        *(bf16x4*)(lds + 2 * XPLANE + n * 256 + byo) = hv;
    }
    __syncthreads();

    // ---- res & skip 1x1 GEMMs: K = 128 over gated, 2-product each
    f32x4 accr[4], accs[4];
#pragma unroll
    for (int nf = 0; nf < 4; ++nf) {
        accr[nf] = (f32x4){0.f, 0.f, 0.f, 0.f};
        accs[nf] = (f32x4){0.f, 0.f, 0.f, 0.f};
    }
#pragma unroll
    for (int ks = 0; ks < 4; ++ks) {
        const size_t wi = ((size_t)(ks * 8 + wave) * 64 + lane) * 8;
        bf16x8 rh = *(const bf16x8*)(Wrh_i + wi);
        bf16x8 rl = *(const bf16x8*)(Wrl_i + wi);
        bf16x8 sh = *(const bf16x8*)(Wsh_i + wi);
        bf16x8 sl = *(const bf16x8*)(Wsl_i + wi);
#pragma unroll
        for (int nf = 0; nf < 4; ++nf) {
            const int col = nf * 16 + l15;
            const int byo = (ks * 64 + lq * 16) ^ ((col & 7) << 4);
            bf16x8 g = *(const bf16x8*)(lds + 2 * XPLANE + col * 256 + byo);
            accr[nf] = __builtin_amdgcn_mfma_f32_16x16x32_bf16(rh, g, accr[nf], 0, 0, 0);
            accr[nf] = __builtin_amdgcn_mfma_f32_16x16x32_bf16(rl, g, accr[nf], 0, 0, 0);
            accs[nf] = __builtin_amdgcn_mfma_f32_16x16x32_bf16(sh, g, accs[nf], 0, 0, 0);
            accs[nf] = __builtin_amdgcn_mfma_f32_16x16x32_bf16(sl, g, accs[nf], 0, 0, 0);
        }
    }

    // ---- epilogue: residual add; Xh from plane 1 (tap1), Xl from global.
    const int nt = TFULL - tile0 < 64 ? TFULL - tile0 : 64;
    const float4 brv = *(const float4*)(br + ch0);
    const float4 bsv = *(const float4*)(bs + ch0);
#pragma unroll
    for (int nf = 0; nf < 4; ++nf) {
        const int n = nf * 16 + l15;
        if (n < nt) {
            const int c = tile0 + n;
            const int byo = (ch0 * 2) ^ ((n & 7) << 4);
            bf16x4 ih = *(const bf16x4*)(lds + XPLANE + n * 256 + byo);
            const size_t off = xbase + (size_t)c * RC + ch0;
            bf16x4 il = *(const bf16x4*)(curl + off);
            bf16x4 oh, ol;
            float sk[4];
#pragma unroll
            for (int r = 0; r < 4; ++r) {
                float inv = bf2f((unsigned short)ih[r]) + bf2f((unsigned short)il[r]);
                float rv = accr[nf][r] + ((const float*)&brv)[r] + inv;
                unsigned short h = f2bf(rv);
                oh[r] = (short)h;
                ol[r] = (short)f2bf(rv - bf2f(h));
                sk[r] = accs[nf][r] + ((const float*)&bsv)[r];
            }
            *(bf16x4*)(nxth + off) = oh;
            *(bf16x4*)(nxtl + off) = ol;
            if (c >= TFULL - SKIP_SZ) {
                float* sp = skip + ((size_t)b * RC + ch0) * SKIP_SZ + (c - (TFULL - SKIP_SZ));
#pragma unroll
                for (int r = 0; r < 4; ++r) sp[(size_t)r * SKIP_SZ] = sk[r];
            }
        }
    }
}

extern "C" void kernel_launch(void* const* d_in, const int* in_sizes, int n_in,
                              void* d_out, int out_size, void* d_ws, size_t ws_size,
                              hipStream_t stream) {
    const float* x  = (const float*)d_in[0];
    const float* Wd = (const float*)d_in[1];
    const float* Wr = (const float*)d_in[2];
    const float* br = (const float*)d_in[3];
    const float* Ws = (const float*)d_in[4];
    const float* bs = (const float*)d_in[5];
    float* out = (float*)d_out;

    const size_t SLOT = (size_t)BATCH * TFULL * RC;
    unsigned short* Xs0h = (unsigned short*)d_ws;
    unsigned short* Xs0l = Xs0h + SLOT;
    unsigned short* Xs1h = Xs0l + SLOT;
    unsigned short* Xs1l = Xs1h + SLOT;
    unsigned short* Wdh = Xs1l + SLOT;
    unsigned short* Wdl = Wdh + (size_t)NB * 32768;
    unsigned short* Wrh = Wdl + (size_t)NB * 32768;
    unsigned short* Wrl = Wrh + (size_t)NB * 16384;
    unsigned short* Wsh = Wrl + (size_t)NB * 16384;
    unsigned short* Wsl = Wsh + (size_t)NB * 16384;

    xpose_split<<<dim3(TFULL / 64, RC / 32, BATCH), 256, 0, stream>>>(x, Xs0h, Xs0l);
    {
        int total = NB * 4096 + 2 * NB * 2048;
        wpack<<<dim3((total + 255) / 256), 256, 0, stream>>>(Wd, Wr, Ws, Wdh, Wdl, Wrh, Wrl, Wsh, Wsl);
    }

    int L = TFULL;
    int pp = 0;
    for (int i = 0; i < NB; ++i) {
        const int d = 1 << (i % 10);
        const int Lout = L - d;
        const int col0 = TFULL - Lout;
        const int units = ((Lout + 63) >> 6) * BATCH;
        unsigned short* curh = pp ? Xs1h : Xs0h;
        unsigned short* curl = pp ? Xs1l : Xs0l;
        unsigned short* nxth = pp ? Xs0h : Xs1h;
        unsigned short* nxtl = pp ? Xs0l : Xs1l;
        wn_step<<<dim3(units), dim3(512), 0, stream>>>(
            curh, curl, nxth, nxtl,
            Wdh + (size_t)i * 32768, Wdl + (size_t)i * 32768,
            Wrh + (size_t)i * 16384, Wrl + (size_t)i * 16384,
            Wsh + (size_t)i * 16384, Wsl + (size_t)i * 16384,
            br + (size_t)i * RC, bs + (size_t)i * RC,
            out + (size_t)i * BATCH * RC * SKIP_SZ, d, col0);
        pp ^= 1;
        L = Lout;
    }
}